// Round 7
// baseline (217.407 us; speedup 1.0000x reference)
//
#include <hip/hip_runtime.h>
#include <hip/hip_cooperative_groups.h>

namespace cg = cooperative_groups;

// GCN forward: two GCNConv layers + linear head.
// Round 7: CSR build fused into ONE cooperative kernel (4 phases w/ grid.sync).
// 5 dispatches total:
//   k_build (coop: hist -> scan -> bucket-scatter -> csr+dinv+prescale)
//   -> k_agg1 -> k_gemm1 -> k_gemm2 -> k_agg2h
// out = dinv[d] * sum_{s in N(d)+self} (dinv[s]*h[s]) per layer.
// Layer1 aggregates BEFORE GEMM (64 feats), layer2 AFTER its GEMM (32 feats).

static constexpr int N  = 50000;
static constexpr int E  = 800000;
static constexpr int F0 = 64;    // input feats
static constexpr int F1 = 128;   // hidden
static constexpr int F2 = 32;    // classes

static constexpr int NBUK   = 196;   // ceil(N/256) buckets of 256 nodes (dst>>8)
static constexpr int CHUNK  = 4096;  // edges per histogram chunk
static constexpr int NCHUNK = 196;   // ceil(E/CHUNK)

// ---- fused CSR build (cooperative, 196 blocks x 256 threads) ----
__global__ __launch_bounds__(256) void k_build(
    const int* __restrict__ src, const int* __restrict__ dst,
    const float* __restrict__ x, int* __restrict__ hist,
    int* __restrict__ bucketTot, unsigned int* __restrict__ ebuf,
    int* __restrict__ cnt, int* __restrict__ rowend, float* __restrict__ dinv,
    int* __restrict__ ssrc, float* __restrict__ xs) {
  cg::grid_group grid = cg::this_grid();
  const int t = threadIdx.x, b = blockIdx.x;   // b < 196 = NCHUNK = NBUK

  // P1: histogram of chunk b over dst buckets
  __shared__ int hl[NBUK];
  for (int i = t; i < NBUK; i += 256) hl[i] = 0;
  __syncthreads();
  {
    int e0 = b * CHUNK, m = min(CHUNK, E - e0);
    for (int i = t; i < m; i += 256)
      atomicAdd(&hl[dst[e0 + i] >> 8], 1);
  }
  __syncthreads();
  for (int i = t; i < NBUK; i += 256) hist[i * NCHUNK + b] = hl[i];
  grid.sync();

  // P2: exclusive scan of bucket-row b over chunks (in place); bucket total
  __shared__ int s1[256];
  {
    int v = (t < NCHUNK) ? hist[b * NCHUNK + t] : 0;
    s1[t] = v; __syncthreads();
    for (int off = 1; off < 256; off <<= 1) {
      int u = (t >= off) ? s1[t - off] : 0;
      __syncthreads(); s1[t] += u; __syncthreads();
    }
    if (t < NCHUNK) hist[b * NCHUNK + t] = s1[t] - v;
    if (t == 255) bucketTot[b] = s1[255];
  }
  grid.sync();

  // P3: scatter chunk b's edges into bucket-grouped ebuf (packed (dlocal<<16)|src)
  __shared__ int tl[256], sl[256], startL[NBUK];
  {
    int v = (t < NBUK) ? bucketTot[t] : 0;
    tl[t] = v; sl[t] = v; __syncthreads();
    for (int off = 1; off < 256; off <<= 1) {
      int u = (t >= off) ? sl[t - off] : 0;
      __syncthreads(); sl[t] += u; __syncthreads();
    }
    for (int i = t; i < NBUK; i += 256)
      startL[i] = (sl[i] - tl[i]) + hist[i * NCHUNK + b];
    __syncthreads();
    int e0 = b * CHUNK, m = min(CHUNK, E - e0);
    for (int i = t; i < m; i += 256) {
      int e = e0 + i;
      int d = dst[e], s = src[e];
      int pos = atomicAdd(&startL[d >> 8], 1);         // LDS atomic
      ebuf[pos] = (unsigned int)s | ((unsigned int)(d & 255) << 16);
    }
  }
  grid.sync();

  // P4: per-bucket CSR finalize (cnt/rowend/dinv + in-bucket sort) + xs prescale
  {
    int base  = sl[b] - tl[b];                         // sl/tl persist from P3
    int m     = tl[b];
    int node0 = b << 8;
    __shared__ int cl[256], sc[256], cur[256];
    __shared__ float dl[256];
    cl[t] = 0;
    __syncthreads();
    for (int i = t; i < m; i += 256)
      atomicAdd(&cl[(ebuf[base + i] >> 16) & 255], 1);
    __syncthreads();
    int v = cl[t];
    sc[t] = v; __syncthreads();
    for (int off = 1; off < 256; off <<= 1) {
      int u = (t >= off) ? sc[t - off] : 0;
      __syncthreads(); sc[t] += u; __syncthreads();
    }
    int excl = sc[t] - v;
    cur[t] = excl;
    float dv = rsqrtf((float)(v + 1));                 // +1 self-loop
    dl[t] = dv;
    int g = node0 + t;
    if (g < N) {
      cnt[g]    = v;
      rowend[g] = base + excl + v;
      dinv[g]   = dv;
    }
    __syncthreads();
    for (int i = t; i < m; i += 256) {
      unsigned int p = ebuf[base + i];
      int d = (p >> 16) & 255;
      int r = atomicAdd(&cur[d], 1);                   // LDS atomic
      ssrc[base + r] = (int)(p & 0xFFFFu);
    }
    // fused prescale: xs[n] = x[n] * dinv[n] for this bucket's 256 nodes
    for (int i = t; i < 256 * (F0 / 4); i += 256) {
      int nl = i >> 4;                                 // local node
      int n = node0 + nl;
      if (n < N) {
        float4 w = reinterpret_cast<const float4*>(x)[n * (F0 / 4) + (i & 15)];
        float d = dl[nl];
        w.x *= d; w.y *= d; w.z *= d; w.w *= d;
        reinterpret_cast<float4*>(xs)[n * (F0 / 4) + (i & 15)] = w;
      }
    }
  }
}

// ---- layer-1 aggregation: AX[n] = dinv[n] * (xs[n] + sum_s xs[s]) ----
__global__ __launch_bounds__(256) void k_agg1(const int* __restrict__ rowend,
    const int* __restrict__ cnt, const int* __restrict__ ssrc,
    const float* __restrict__ xs, const float* __restrict__ dinv,
    float* __restrict__ AX) {
  int gw = (blockIdx.x * 256 + threadIdx.x) >> 6;   // node (one wave each)
  int lane = threadIdx.x & 63;                      // feature
  if (gw >= N) return;
  int end   = __builtin_amdgcn_readfirstlane(rowend[gw]);
  int deg   = __builtin_amdgcn_readfirstlane(cnt[gw]);
  int start = end - deg;
  float a0 = xs[(size_t)gw * F0 + lane];            // self loop (already *dinv)
  float a1 = 0.f, a2 = 0.f, a3 = 0.f;
  for (int e0 = start; e0 < end; e0 += 8) {
    #pragma unroll
    for (int u = 0; u < 8; ++u) {
      int j  = e0 + u;
      int jc = (j < end) ? j : start;               // uniform clamp
      int s  = ssrc[jc];                            // wave-uniform -> s_load
      float v = xs[(size_t)s * F0 + lane];
      v = (j < end) ? v : 0.f;                      // uniform mask
      if ((u & 3) == 0) a0 += v;
      else if ((u & 3) == 1) a1 += v;
      else if ((u & 3) == 2) a2 += v;
      else a3 += v;
    }
  }
  AX[(size_t)gw * F0 + lane] = ((a0 + a2) + (a1 + a3)) * dinv[gw];
}

// ---- GEMM1: H1r = relu(AX @ W1 + b1), 64x128 tile, 4r x 8c per thread ----
// W1 in LDS with XOR float4-slot swizzle (slot p = s ^ (s>>2)) so the 16
// column-groups' stride-8-slot reads spread 2-way across bank quads (free).
__global__ __launch_bounds__(256) void k_gemm1(const float* __restrict__ AX,
    const float* __restrict__ W1, const float* __restrict__ b1,
    float* __restrict__ H1r) {
  __shared__ float Ws[F0 * F1];      // 32 KB, [64][32 float4-slots] swizzled
  __shared__ float Xs[64][F0 + 4];   // 17.4 KB, stride 68 -> clean broadcast
  const int tid = threadIdx.x;
  const int row0 = blockIdx.x * 64;
  float4* Wsf4 = reinterpret_cast<float4*>(Ws);
  for (int i = tid; i < F0 * F1 / 4; i += 256) {
    int k = i >> 5, s = i & 31;
    int p = s ^ (s >> 2);
    Wsf4[k * 32 + p] = reinterpret_cast<const float4*>(W1)[i];
  }
  for (int i = tid; i < 64 * 16; i += 256) {
    int r = i >> 4, c4 = i & 15;
    int n = row0 + r;
    float4 v = make_float4(0.f, 0.f, 0.f, 0.f);
    if (n < N) v = reinterpret_cast<const float4*>(AX)[n * 16 + c4];
    *reinterpret_cast<float4*>(&Xs[r][c4 * 4]) = v;
  }
  __syncthreads();
  const int cg = tid & 15, rg = tid >> 4;
  const int c0 = cg * 8;
  const int s0 = 2 * cg, s1 = 2 * cg + 1;
  const int p0 = s0 ^ (s0 >> 2), p1 = s1 ^ (s1 >> 2);
  float acc[4][8];
  #pragma unroll
  for (int i = 0; i < 4; ++i)
    #pragma unroll
    for (int j = 0; j < 8; ++j) acc[i][j] = 0.f;
  for (int k0 = 0; k0 < F0; k0 += 4) {
    float x0[4], x1[4], x2[4], x3[4];
    *reinterpret_cast<float4*>(x0) = *reinterpret_cast<const float4*>(&Xs[rg * 4 + 0][k0]);
    *reinterpret_cast<float4*>(x1) = *reinterpret_cast<const float4*>(&Xs[rg * 4 + 1][k0]);
    *reinterpret_cast<float4*>(x2) = *reinterpret_cast<const float4*>(&Xs[rg * 4 + 2][k0]);
    *reinterpret_cast<float4*>(x3) = *reinterpret_cast<const float4*>(&Xs[rg * 4 + 3][k0]);
    #pragma unroll
    for (int kk = 0; kk < 4; ++kk) {
      float w[8];
      *reinterpret_cast<float4*>(w)     = Wsf4[(k0 + kk) * 32 + p0];
      *reinterpret_cast<float4*>(w + 4) = Wsf4[(k0 + kk) * 32 + p1];
      #pragma unroll
      for (int j = 0; j < 8; ++j) {
        acc[0][j] = fmaf(x0[kk], w[j], acc[0][j]);
        acc[1][j] = fmaf(x1[kk], w[j], acc[1][j]);
        acc[2][j] = fmaf(x2[kk], w[j], acc[2][j]);
        acc[3][j] = fmaf(x3[kk], w[j], acc[3][j]);
      }
    }
  }
  float bb[8];
  *reinterpret_cast<float4*>(bb)     = *reinterpret_cast<const float4*>(&b1[c0]);
  *reinterpret_cast<float4*>(bb + 4) = *reinterpret_cast<const float4*>(&b1[c0 + 4]);
  #pragma unroll
  for (int i = 0; i < 4; ++i) {
    int n = row0 + rg * 4 + i;
    if (n < N) {
      float o[8];
      #pragma unroll
      for (int j = 0; j < 8; ++j) o[j] = fmaxf(acc[i][j] + bb[j], 0.f);
      *reinterpret_cast<float4*>(&H1r[(size_t)n * F1 + c0])     = *reinterpret_cast<float4*>(o);
      *reinterpret_cast<float4*>(&H1r[(size_t)n * F1 + c0 + 4]) = *reinterpret_cast<float4*>(o + 4);
    }
  }
}

// ---- GEMM2: H2s = (H1r @ W2) * dinv, 128-row tile, 2r x 8c per thread ----
// H1 rows read directly from global (4x redundancy, L2/L3-served); only W2 in LDS.
__global__ __launch_bounds__(256) void k_gemm2(const float* __restrict__ H1r,
    const float* __restrict__ dinv, const float* __restrict__ W2,
    float* __restrict__ H2s) {
  __shared__ float Ws[F1 * F2];      // 16 KB
  const int tid = threadIdx.x;
  const int row0 = blockIdx.x * 128;
  float4* Wsf4 = reinterpret_cast<float4*>(Ws);
  for (int i = tid; i < F1 * F2 / 4; i += 256)
    Wsf4[i] = reinterpret_cast<const float4*>(W2)[i];
  __syncthreads();
  const int cg = tid & 3, rg = tid >> 2;           // cols cg*8.. ; rows rg*2..
  const int c0 = cg * 8;
  const int n0 = row0 + rg * 2, n1 = n0 + 1;
  const int na = (n0 < N) ? n0 : 0, nb = (n1 < N) ? n1 : 0;
  const float4* X0 = reinterpret_cast<const float4*>(H1r + (size_t)na * F1);
  const float4* X1 = reinterpret_cast<const float4*>(H1r + (size_t)nb * F1);
  float acc[2][8];
  #pragma unroll
  for (int i = 0; i < 2; ++i)
    #pragma unroll
    for (int j = 0; j < 8; ++j) acc[i][j] = 0.f;
  for (int k0 = 0; k0 < F1; k0 += 4) {
    float x0[4], x1[4];
    *reinterpret_cast<float4*>(x0) = X0[k0 >> 2];
    *reinterpret_cast<float4*>(x1) = X1[k0 >> 2];
    #pragma unroll
    for (int kk = 0; kk < 4; ++kk) {
      float w[8];
      *reinterpret_cast<float4*>(w)     = Wsf4[(k0 + kk) * 8 + cg * 2];
      *reinterpret_cast<float4*>(w + 4) = Wsf4[(k0 + kk) * 8 + cg * 2 + 1];
      #pragma unroll
      for (int j = 0; j < 8; ++j) {
        acc[0][j] = fmaf(x0[kk], w[j], acc[0][j]);
        acc[1][j] = fmaf(x1[kk], w[j], acc[1][j]);
      }
    }
  }
  #pragma unroll
  for (int i = 0; i < 2; ++i) {
    int n = n0 + i;
    if (n < N) {
      float d = dinv[n];
      float o[8];
      #pragma unroll
      for (int j = 0; j < 8; ++j) o[j] = acc[i][j] * d;
      *reinterpret_cast<float4*>(&H2s[(size_t)n * F2 + c0])     = *reinterpret_cast<float4*>(o);
      *reinterpret_cast<float4*>(&H2s[(size_t)n * F2 + c0 + 4]) = *reinterpret_cast<float4*>(o + 4);
    }
  }
}

// ---- fused layer-2 aggregation + bias + head ----
// h2[n] = dinv[n]*(H2s[n] + sum_s H2s[s]) + b2 ; out[n] = h2[n] @ Wc + bc
__global__ __launch_bounds__(256) void k_agg2h(const int* __restrict__ rowend,
    const int* __restrict__ cnt, const int* __restrict__ ssrc,
    const float* __restrict__ H2s, const float* __restrict__ dinv,
    const float* __restrict__ b2, const float* __restrict__ Wc,
    const float* __restrict__ bc, float* __restrict__ h2,
    float* __restrict__ out) {
  __shared__ float Wcs[F2][F2];  // 4 KB
  const int tid = threadIdx.x;
  for (int i = tid; i < F2 * F2; i += 256) Wcs[i >> 5][i & 31] = Wc[i];
  __syncthreads();
  int gw = (blockIdx.x * 256 + tid) >> 6;           // node (one wave each)
  int lane = tid & 63;
  int f = lane & 31, half = lane >> 5;
  if (gw >= N) return;
  int end   = __builtin_amdgcn_readfirstlane(rowend[gw]);
  int deg   = __builtin_amdgcn_readfirstlane(cnt[gw]);
  int start = end - deg;
  float a0 = (half == 0) ? H2s[(size_t)gw * F2 + f] : 0.f;  // self loop
  float a1 = 0.f, a2 = 0.f, a3 = 0.f;
  for (int e0 = start; e0 < end; e0 += 8) {
    #pragma unroll
    for (int u = 0; u < 4; ++u) {
      int ja = e0 + 2 * u, jb = ja + 1;
      int sa = ssrc[(ja < end) ? ja : start];       // uniform -> s_load
      int sb = ssrc[(jb < end) ? jb : start];
      int s  = half ? sb : sa;
      int j  = half ? jb : ja;
      float v = H2s[(size_t)s * F2 + f];
      v = (j < end) ? v : 0.f;
      if (u == 0) a0 += v;
      else if (u == 1) a1 += v;
      else if (u == 2) a2 += v;
      else a3 += v;
    }
  }
  float acc = (a0 + a2) + (a1 + a3);
  acc += __shfl_xor(acc, 32);
  float h2v = dinv[gw] * acc + b2[f];               // valid in all 64 lanes
  if (half == 0) h2[(size_t)gw * F2 + f] = h2v;
  // head: out[gw][f] = bc[f] + sum_k h2v(k) * Wc[k][f]; halves split k range
  float acco = 0.f;
  #pragma unroll
  for (int kk = 0; kk < 16; ++kk) {
    int k = kk + 16 * half;
    float hk = __shfl(h2v, k);                      // lane k holds feature k
    acco += hk * Wcs[k][f];
  }
  acco += __shfl_xor(acco, 32);
  if (half == 0) out[(size_t)gw * F2 + f] = acco + bc[f];
}

extern "C" void kernel_launch(void* const* d_in, const int* in_sizes, int n_in,
                              void* d_out, int out_size, void* d_ws, size_t ws_size,
                              hipStream_t stream) {
  const float* x  = (const float*)d_in[0];
  const int*   ei = (const int*)d_in[1];
  const int*   srcp = ei;                // edge_index[0]
  const int*   dstp = ei + E;            // edge_index[1]
  const float* W1 = (const float*)d_in[2];
  const float* b1 = (const float*)d_in[3];
  const float* W2 = (const float*)d_in[4];
  const float* b2 = (const float*)d_in[5];
  const float* Wc = (const float*)d_in[6];
  const float* bc = (const float*)d_in[7];

  float* out = (float*)d_out;                    // [N, 32] logits
  float* h2  = out + (size_t)N * F2;             // [N, 32] hidden output

  // workspace layout (~66 MB of 256 MB) — all disjoint, no aliasing
  int*   cnt        = (int*)d_ws;                // N
  int*   rowend     = cnt + N;                   // N
  int*   bucketTot  = rowend + N;                // 256
  float* dinv       = (float*)(bucketTot + 256); // N
  int*   ssrc       = (int*)(dinv + N);          // E
  unsigned int* ebuf = (unsigned int*)(ssrc + E);// E
  int*   hist       = (int*)(ebuf + E);          // NBUK*NCHUNK
  float* xs         = (float*)(hist + NBUK * NCHUNK + 64); // N*64
  float* AX         = xs + (size_t)N * F0;       // N*64
  float* H1r        = AX + (size_t)N * F0;       // N*128
  float* H2s        = H1r + (size_t)N * F1;      // N*32

  void* build_args[] = {
    (void*)&srcp, (void*)&dstp, (void*)&x, (void*)&hist, (void*)&bucketTot,
    (void*)&ebuf, (void*)&cnt, (void*)&rowend, (void*)&dinv, (void*)&ssrc,
    (void*)&xs
  };
  hipLaunchCooperativeKernel((void*)k_build, dim3(NCHUNK), dim3(256),
                             build_args, 0, stream);

  k_agg1 <<<(N + 3) / 4, 256, 0, stream>>>(rowend, cnt, ssrc, xs, dinv, AX);
  k_gemm1<<<(N + 63) / 64, 256, 0, stream>>>(AX, W1, b1, H1r);
  k_gemm2<<<(N + 127) / 128, 256, 0, stream>>>(H1r, dinv, W2, H2s);
  k_agg2h<<<(N + 3) / 4, 256, 0, stream>>>(rowend, cnt, ssrc, H2s, dinv, b2, Wc, bc, h2, out);
}

// Round 8
// 140.996 us; speedup vs baseline: 1.5419x; 1.5419x over previous
//
#include <hip/hip_runtime.h>

// GCN forward: two GCNConv layers + linear head.
// Round 8: round-6 structure (coop grid.sync regressed 135->217us; reverted).
// GEMMs: 128-thread 8x8-register-tile gemm1 fused with register-tiled gemm2
// via LDS overlay (phase A: Ws1+Xs -> phase B: H1s+Ws2). 7 dispatches:
//   k_hist -> k_scanbk -> k_bucket -> k_csr(+dinv+prescale) ->
//   k_agg1 -> k_gemm12 -> k_agg2h
// out = dinv[d] * sum_{s in N(d)+self} (dinv[s]*h[s]) per layer.
// Layer1 aggregates BEFORE GEMM (64 feats), layer2 AFTER its GEMM (32 feats).

static constexpr int N  = 50000;
static constexpr int E  = 800000;
static constexpr int F0 = 64;    // input feats
static constexpr int F1 = 128;   // hidden
static constexpr int F2 = 32;    // classes

static constexpr int NBUK   = 196;   // ceil(N/256) buckets of 256 nodes (dst>>8)
static constexpr int CHUNK  = 4096;  // edges per histogram chunk
static constexpr int NCHUNK = 196;   // ceil(E/CHUNK)

// ---- B1: per-chunk LDS histogram over dst buckets ----
__global__ __launch_bounds__(256) void k_hist(const int* __restrict__ dst,
                                              int* __restrict__ hist) {
  __shared__ int hl[NBUK];
  int tid = threadIdx.x, c = blockIdx.x;
  for (int t = tid; t < NBUK; t += 256) hl[t] = 0;
  __syncthreads();
  int e0 = c * CHUNK, m = min(CHUNK, E - e0);
  for (int i = tid; i < m; i += 256)
    atomicAdd(&hl[dst[e0 + i] >> 8], 1);
  __syncthreads();
  for (int t = tid; t < NBUK; t += 256) hist[t * NCHUNK + c] = hl[t];
}

// ---- S1: per-bucket exclusive scan over chunks (in place); bucket totals out ----
__global__ __launch_bounds__(256) void k_scanbk(int* __restrict__ hist,
                                                int* __restrict__ bucketTot) {
  __shared__ int s[256];
  int t = threadIdx.x, b = blockIdx.x;
  int v = (t < NCHUNK) ? hist[b * NCHUNK + t] : 0;
  s[t] = v; __syncthreads();
  for (int off = 1; off < 256; off <<= 1) {
    int u = (t >= off) ? s[t - off] : 0;
    __syncthreads(); s[t] += u; __syncthreads();
  }
  if (t < NCHUNK) hist[b * NCHUNK + t] = s[t] - v;
  if (t == 255) bucketTot[b] = s[255];
}

// ---- B2: scatter edges into bucket-grouped order (packed (dlocal<<16)|src) ----
__global__ __launch_bounds__(256) void k_bucket(const int* __restrict__ src,
    const int* __restrict__ dst, const int* __restrict__ hist,
    const int* __restrict__ bucketTot, unsigned int* __restrict__ ebuf) {
  __shared__ int tl[256], sl[256], startL[NBUK];
  int tid = threadIdx.x, c = blockIdx.x;
  int v = (tid < NBUK) ? bucketTot[tid] : 0;
  tl[tid] = v; sl[tid] = v; __syncthreads();
  for (int off = 1; off < 256; off <<= 1) {
    int u = (tid >= off) ? sl[tid - off] : 0;
    __syncthreads(); sl[tid] += u; __syncthreads();
  }
  for (int t = tid; t < NBUK; t += 256)
    startL[t] = (sl[t] - tl[t]) + hist[t * NCHUNK + c];
  __syncthreads();
  int e0 = c * CHUNK, m = min(CHUNK, E - e0);
  for (int i = tid; i < m; i += 256) {
    int e = e0 + i;
    int d = dst[e], s = src[e];
    int pos = atomicAdd(&startL[d >> 8], 1);           // LDS atomic
    ebuf[pos] = (unsigned int)s | ((unsigned int)(d & 255) << 16);
  }
}

// ---- B3: per-bucket CSR finalize (cnt/rowend/dinv + in-bucket sort) + xs prescale ----
__global__ __launch_bounds__(256) void k_csr(const unsigned int* __restrict__ ebuf,
    const int* __restrict__ bucketTot, const float* __restrict__ x,
    int* __restrict__ cnt, int* __restrict__ rowend, float* __restrict__ dinv,
    int* __restrict__ ssrc, float* __restrict__ xs) {
  __shared__ int tl[256], sl[256], cl[256], sc[256], cur[256];
  __shared__ float dl[256];
  int t = threadIdx.x, b = blockIdx.x;
  // scan bucket totals to get this bucket's base
  int v0 = (t < NBUK) ? bucketTot[t] : 0;
  tl[t] = v0; sl[t] = v0; __syncthreads();
  for (int off = 1; off < 256; off <<= 1) {
    int u = (t >= off) ? sl[t - off] : 0;
    __syncthreads(); sl[t] += u; __syncthreads();
  }
  int base = sl[b] - tl[b];
  int m    = tl[b];
  int node0 = b << 8;
  cl[t] = 0;
  __syncthreads();
  for (int i = t; i < m; i += 256)
    atomicAdd(&cl[(ebuf[base + i] >> 16) & 255], 1);
  __syncthreads();
  int v = cl[t];
  sc[t] = v; __syncthreads();
  for (int off = 1; off < 256; off <<= 1) {
    int u = (t >= off) ? sc[t - off] : 0;
    __syncthreads(); sc[t] += u; __syncthreads();
  }
  int excl = sc[t] - v;
  cur[t] = excl;
  float dv = rsqrtf((float)(v + 1));                  // +1 self-loop
  dl[t] = dv;
  int g = node0 + t;
  if (g < N) {
    cnt[g]    = v;
    rowend[g] = base + excl + v;
    dinv[g]   = dv;
  }
  __syncthreads();
  for (int i = t; i < m; i += 256) {
    unsigned int p = ebuf[base + i];
    int d = (p >> 16) & 255;
    int r = atomicAdd(&cur[d], 1);                     // LDS atomic
    ssrc[base + r] = (int)(p & 0xFFFFu);
  }
  // fused prescale: xs[n] = x[n] * dinv[n] for this bucket's 256 nodes
  for (int i = t; i < 256 * (F0 / 4); i += 256) {
    int nl = i >> 4;                                   // local node
    int n = node0 + nl;
    if (n < N) {
      float4 w = reinterpret_cast<const float4*>(x)[n * (F0 / 4) + (i & 15)];
      float d = dl[nl];
      w.x *= d; w.y *= d; w.z *= d; w.w *= d;
      reinterpret_cast<float4*>(xs)[n * (F0 / 4) + (i & 15)] = w;
    }
  }
}

// ---- layer-1 aggregation: AX[n] = dinv[n] * (xs[n] + sum_s xs[s]) ----
__global__ __launch_bounds__(256) void k_agg1(const int* __restrict__ rowend,
    const int* __restrict__ cnt, const int* __restrict__ ssrc,
    const float* __restrict__ xs, const float* __restrict__ dinv,
    float* __restrict__ AX) {
  int gw = (blockIdx.x * 256 + threadIdx.x) >> 6;   // node (one wave each)
  int lane = threadIdx.x & 63;                      // feature
  if (gw >= N) return;
  int end   = __builtin_amdgcn_readfirstlane(rowend[gw]);
  int deg   = __builtin_amdgcn_readfirstlane(cnt[gw]);
  int start = end - deg;
  float a0 = xs[(size_t)gw * F0 + lane];            // self loop (already *dinv)
  float a1 = 0.f, a2 = 0.f, a3 = 0.f;
  for (int e0 = start; e0 < end; e0 += 8) {
    #pragma unroll
    for (int u = 0; u < 8; ++u) {
      int j  = e0 + u;
      int jc = (j < end) ? j : start;               // uniform clamp
      int s  = ssrc[jc];                            // wave-uniform -> s_load
      float v = xs[(size_t)s * F0 + lane];
      v = (j < end) ? v : 0.f;                      // uniform mask
      if ((u & 3) == 0) a0 += v;
      else if ((u & 3) == 1) a1 += v;
      else if ((u & 3) == 2) a2 += v;
      else a3 += v;
    }
  }
  AX[(size_t)gw * F0 + lane] = ((a0 + a2) + (a1 + a3)) * dinv[gw];
}

// ---- fused register-tiled GEMM1+relu+GEMM2: H2s = relu(AX@W1+b1)@W2 * dinv ----
// 128 threads, 64-row tile. Phase A: 8r x 8c per thread (rows strided by 8,
// 16 b128 LDS reads per 256 FMA). Overlay sync. Phase B: 4r x 4c per thread
// (rows strided by 16, 8 b128 per 64 FMA). LDS arena 50176 B -> 3 blocks/CU.
__global__ __launch_bounds__(128) void k_gemm12(const float* __restrict__ AX,
    const float* __restrict__ W1, const float* __restrict__ b1,
    const float* __restrict__ W2, const float* __restrict__ dinv,
    float* __restrict__ H2s) {
  __shared__ float arena[12544];           // 50176 B
  float* Ws1 = arena;                      // phase A: [64][32 f4-slots] = 8192 f
  float* Xs  = arena + 8192;               // phase A: [64][68] = 4352 f
  float* H1s = arena;                      // phase B: [64][132] = 8448 f
  float* Ws2 = arena + 8448;               // phase B: [128][32] = 4096 f
  const int tid = threadIdx.x;
  const int row0 = blockIdx.x * 64;
  float4* Ws1f4 = reinterpret_cast<float4*>(Ws1);
  // stage W1 (swizzled f4 slots: p = s ^ (s>>2)) and X tile
  for (int i = tid; i < F0 * F1 / 4; i += 128) {
    int k = i >> 5, s = i & 31;
    int p = s ^ (s >> 2);
    Ws1f4[k * 32 + p] = reinterpret_cast<const float4*>(W1)[i];
  }
  for (int i = tid; i < 64 * 16; i += 128) {
    int r = i >> 4, c4 = i & 15;
    int n = row0 + r;
    float4 v = make_float4(0.f, 0.f, 0.f, 0.f);
    if (n < N) v = reinterpret_cast<const float4*>(AX)[n * 16 + c4];
    *reinterpret_cast<float4*>(&Xs[r * 68 + c4 * 4]) = v;
  }
  __syncthreads();
  // phase A: thread owns rows {rg + 8i} (i=0..7), cols c0..c0+7
  const int cg = tid & 15, rg = tid >> 4;          // cg 0..15, rg 0..7
  const int c0 = cg * 8;
  const int sa = 2 * cg, sb = 2 * cg + 1;
  const int p0 = sa ^ (sa >> 2), p1 = sb ^ (sb >> 2);
  float acc[8][8];
  #pragma unroll
  for (int i = 0; i < 8; ++i)
    #pragma unroll
    for (int j = 0; j < 8; ++j) acc[i][j] = 0.f;
  for (int k0 = 0; k0 < F0; k0 += 4) {
    float xr[8][4];
    #pragma unroll
    for (int i = 0; i < 8; ++i)
      *reinterpret_cast<float4*>(xr[i]) =
          *reinterpret_cast<const float4*>(&Xs[(rg + 8 * i) * 68 + k0]);
    #pragma unroll
    for (int kk = 0; kk < 4; ++kk) {
      float w[8];
      *reinterpret_cast<float4*>(w)     = Ws1f4[(k0 + kk) * 32 + p0];
      *reinterpret_cast<float4*>(w + 4) = Ws1f4[(k0 + kk) * 32 + p1];
      #pragma unroll
      for (int i = 0; i < 8; ++i)
        #pragma unroll
        for (int j = 0; j < 8; ++j)
          acc[i][j] = fmaf(xr[i][kk], w[j], acc[i][j]);
    }
  }
  float bb[8];
  *reinterpret_cast<float4*>(bb)     = *reinterpret_cast<const float4*>(&b1[c0]);
  *reinterpret_cast<float4*>(bb + 4) = *reinterpret_cast<const float4*>(&b1[c0 + 4]);
  __syncthreads();                                  // all Ws1/Xs reads done
  // overlay: write relu'd H1 tile; co-load W2
  #pragma unroll
  for (int i = 0; i < 8; ++i) {
    int r = rg + 8 * i;
    float o[8];
    #pragma unroll
    for (int j = 0; j < 8; ++j) o[j] = fmaxf(acc[i][j] + bb[j], 0.f);
    *reinterpret_cast<float4*>(&H1s[r * 132 + c0])     = *reinterpret_cast<float4*>(o);
    *reinterpret_cast<float4*>(&H1s[r * 132 + c0 + 4]) = *reinterpret_cast<float4*>(o + 4);
  }
  float4* Ws2f4 = reinterpret_cast<float4*>(Ws2);
  for (int i = tid; i < F1 * F2 / 4; i += 128)
    Ws2f4[i] = reinterpret_cast<const float4*>(W2)[i];
  __syncthreads();
  // phase B: thread owns rows {rg2 + 16m} (m=0..3), cols c0b..c0b+3
  const int rg2 = tid & 15, cg2 = tid >> 4;        // rg2 0..15, cg2 0..7
  const int c0b = cg2 * 4;
  float acc2[4][4];
  #pragma unroll
  for (int m = 0; m < 4; ++m)
    #pragma unroll
    for (int j = 0; j < 4; ++j) acc2[m][j] = 0.f;
  for (int k0 = 0; k0 < F1; k0 += 4) {
    float h[4][4];
    #pragma unroll
    for (int m = 0; m < 4; ++m)
      *reinterpret_cast<float4*>(h[m]) =
          *reinterpret_cast<const float4*>(&H1s[(rg2 + 16 * m) * 132 + k0]);
    #pragma unroll
    for (int kk = 0; kk < 4; ++kk) {
      float w[4];
      *reinterpret_cast<float4*>(w) = Ws2f4[(k0 + kk) * 8 + cg2];
      #pragma unroll
      for (int m = 0; m < 4; ++m)
        #pragma unroll
        for (int j = 0; j < 4; ++j)
          acc2[m][j] = fmaf(h[m][kk], w[j], acc2[m][j]);
    }
  }
  #pragma unroll
  for (int m = 0; m < 4; ++m) {
    int n = row0 + rg2 + 16 * m;
    if (n < N) {
      float d = dinv[n];
      float o[4];
      #pragma unroll
      for (int j = 0; j < 4; ++j) o[j] = acc2[m][j] * d;
      *reinterpret_cast<float4*>(&H2s[(size_t)n * F2 + c0b]) = *reinterpret_cast<float4*>(o);
    }
  }
}

// ---- fused layer-2 aggregation + bias + head ----
// h2[n] = dinv[n]*(H2s[n] + sum_s H2s[s]) + b2 ; out[n] = h2[n] @ Wc + bc
__global__ __launch_bounds__(256) void k_agg2h(const int* __restrict__ rowend,
    const int* __restrict__ cnt, const int* __restrict__ ssrc,
    const float* __restrict__ H2s, const float* __restrict__ dinv,
    const float* __restrict__ b2, const float* __restrict__ Wc,
    const float* __restrict__ bc, float* __restrict__ h2,
    float* __restrict__ out) {
  __shared__ float Wcs[F2][F2];  // 4 KB
  const int tid = threadIdx.x;
  for (int i = tid; i < F2 * F2; i += 256) Wcs[i >> 5][i & 31] = Wc[i];
  __syncthreads();
  int gw = (blockIdx.x * 256 + tid) >> 6;           // node (one wave each)
  int lane = tid & 63;
  int f = lane & 31, half = lane >> 5;
  if (gw >= N) return;
  int end   = __builtin_amdgcn_readfirstlane(rowend[gw]);
  int deg   = __builtin_amdgcn_readfirstlane(cnt[gw]);
  int start = end - deg;
  float a0 = (half == 0) ? H2s[(size_t)gw * F2 + f] : 0.f;  // self loop
  float a1 = 0.f, a2 = 0.f, a3 = 0.f;
  for (int e0 = start; e0 < end; e0 += 8) {
    #pragma unroll
    for (int u = 0; u < 4; ++u) {
      int ja = e0 + 2 * u, jb = ja + 1;
      int sa = ssrc[(ja < end) ? ja : start];       // uniform -> s_load
      int sb = ssrc[(jb < end) ? jb : start];
      int s  = half ? sb : sa;
      int j  = half ? jb : ja;
      float v = H2s[(size_t)s * F2 + f];
      v = (j < end) ? v : 0.f;
      if (u == 0) a0 += v;
      else if (u == 1) a1 += v;
      else if (u == 2) a2 += v;
      else a3 += v;
    }
  }
  float acc = (a0 + a2) + (a1 + a3);
  acc += __shfl_xor(acc, 32);
  float h2v = dinv[gw] * acc + b2[f];               // valid in all 64 lanes
  if (half == 0) h2[(size_t)gw * F2 + f] = h2v;
  // head: out[gw][f] = bc[f] + sum_k h2v(k) * Wc[k][f]; halves split k range
  float acco = 0.f;
  #pragma unroll
  for (int kk = 0; kk < 16; ++kk) {
    int k = kk + 16 * half;
    float hk = __shfl(h2v, k);                      // lane k holds feature k
    acco += hk * Wcs[k][f];
  }
  acco += __shfl_xor(acco, 32);
  if (half == 0) out[(size_t)gw * F2 + f] = acco + bc[f];
}

extern "C" void kernel_launch(void* const* d_in, const int* in_sizes, int n_in,
                              void* d_out, int out_size, void* d_ws, size_t ws_size,
                              hipStream_t stream) {
  const float* x  = (const float*)d_in[0];
  const int*   ei = (const int*)d_in[1];
  const int*   src = ei;                 // edge_index[0]
  const int*   dst = ei + E;             // edge_index[1]
  const float* W1 = (const float*)d_in[2];
  const float* b1 = (const float*)d_in[3];
  const float* W2 = (const float*)d_in[4];
  const float* b2 = (const float*)d_in[5];
  const float* Wc = (const float*)d_in[6];
  const float* bc = (const float*)d_in[7];

  float* out = (float*)d_out;                    // [N, 32] logits
  float* h2  = out + (size_t)N * F2;             // [N, 32] hidden output

  // workspace layout (~40 MB of 256 MB) — all disjoint, no aliasing
  int*   cnt        = (int*)d_ws;                // N
  int*   rowend     = cnt + N;                   // N
  int*   bucketTot  = rowend + N;                // 256
  float* dinv       = (float*)(bucketTot + 256); // N
  int*   ssrc       = (int*)(dinv + N);          // E
  unsigned int* ebuf = (unsigned int*)(ssrc + E);// E
  int*   hist       = (int*)(ebuf + E);          // NBUK*NCHUNK
  float* xs         = (float*)(hist + NBUK * NCHUNK + 64); // N*64
  float* AX         = xs + (size_t)N * F0;       // N*64
  float* H2s        = AX + (size_t)N * F0;       // N*32

  k_hist   <<<NCHUNK, 256, 0, stream>>>(dst, hist);
  k_scanbk <<<NBUK,   256, 0, stream>>>(hist, bucketTot);
  k_bucket <<<NCHUNK, 256, 0, stream>>>(src, dst, hist, bucketTot, ebuf);
  k_csr    <<<NBUK,   256, 0, stream>>>(ebuf, bucketTot, x, cnt, rowend, dinv, ssrc, xs);

  k_agg1  <<<(N + 3) / 4, 256, 0, stream>>>(rowend, cnt, ssrc, xs, dinv, AX);
  k_gemm12<<<(N + 63) / 64, 128, 0, stream>>>(AX, W1, b1, W2, dinv, H2s);
  k_agg2h <<<(N + 3) / 4, 256, 0, stream>>>(rowend, cnt, ssrc, H2s, dinv, b2, Wc, bc, h2, out);
}